// Round 9
// baseline (171.511 us; speedup 1.0000x reference)
//
#include <hip/hip_runtime.h>

// DA-RNN decoder: 256 blocks (1/CU) x 512 threads, 32 sequential steps in-block.
// All weights register-resident f16 (W1a quarter 32 VGPR + 4 gate-row slices
// 64 VGPR) under __launch_bounds__(512,2) (256-VGPR budget, honored R6/R7).
// LDS transfers per step minimized to 3 (A, logits, h/c):
//  ph1: thread (g,s4): A[g] partial over [h;c] slice 64 + ALL FOUR gate rows
//       (j*128+g) partials over h slice 32; shuffle-consolidate -> s4==0 thread
//       holds (i,f,g,o) dots in REGISTERS; write A to LDS.               B1
//  ph2: logits[t] = b2 + W2 . tanh(A + Epre[t])  (16 thr/t).             B2
//  ph3: EVERY wave: in-wave softmax + y_tilde (q-trick); cell threads
//       (s4==0) apply gates from regs -> LSTM -> publish h,c (4 bank-
//       staggered copies, conflict-free fan-out reads in ph1).           B3
// ctx materialized once after the loop from final attn weights.
// (Resubmission of R8 — previous run died on container infra, no data.)

#define TT 32

typedef _Float16 h2_t __attribute__((ext_vector_type(2)));
typedef _Float16 h4_t __attribute__((ext_vector_type(4)));
typedef _Float16 h8_t __attribute__((ext_vector_type(8)));

#if __has_builtin(__builtin_amdgcn_fdot2)
#define FDOT2(a, b, c) __builtin_amdgcn_fdot2((a), (b), (c), false)
#else
static __device__ __forceinline__ float FDOT2(h2_t a, h2_t b, float c) {
    return c + (float)a[0] * (float)b[0] + (float)a[1] * (float)b[1];
}
#endif

__device__ __forceinline__ float dot_h8(h8_t w, h8_t v, float acc) {
    acc = FDOT2(__builtin_shufflevector(w, w, 0, 1), __builtin_shufflevector(v, v, 0, 1), acc);
    acc = FDOT2(__builtin_shufflevector(w, w, 2, 3), __builtin_shufflevector(v, v, 2, 3), acc);
    acc = FDOT2(__builtin_shufflevector(w, w, 4, 5), __builtin_shufflevector(v, v, 4, 5), acc);
    acc = FDOT2(__builtin_shufflevector(w, w, 6, 7), __builtin_shufflevector(v, v, 6, 7), acc);
    return acc;
}
__device__ __forceinline__ h8_t pk8(float4 a, float4 b) {
    h8_t r;
    r[0] = (_Float16)a.x; r[1] = (_Float16)a.y; r[2] = (_Float16)a.z; r[3] = (_Float16)a.w;
    r[4] = (_Float16)b.x; r[5] = (_Float16)b.y; r[6] = (_Float16)b.z; r[7] = (_Float16)b.w;
    return r;
}
__device__ __forceinline__ float fast_tanh(float x) {
    float e = __expf(2.f * x);
    return 1.f - __fdividef(2.f, e + 1.f);
}
__device__ __forceinline__ float fast_sig(float x) {
    return __fdividef(1.f, 1.f + __expf(-x));
}

__global__ __launch_bounds__(512, 2) void decoder_kernel(
    const float* __restrict__ enc_g,  // [B,32,128]
    const float* __restrict__ yh_g,   // [B,32,1]
    const float* __restrict__ W1,     // [128,384] cols [h|c|enc]
    const float* __restrict__ b1,     // [128]
    const float* __restrict__ W2,     // [1,128]
    const float* __restrict__ b2,     // [1]
    const float* __restrict__ Wih,    // [512,1]
    const float* __restrict__ Whh,    // [512,128]
    const float* __restrict__ bih,    // [512]
    const float* __restrict__ bhh,    // [512]
    const float* __restrict__ fcW,    // [1,129]
    const float* __restrict__ fcB,    // [1]
    const float* __restrict__ fcfW,   // [1,256]
    const float* __restrict__ fcfB,   // [1]
    float* __restrict__ out)          // [B,1]
{
    __shared__ __align__(16) _Float16 s_enc16[TT * 136];   // 8704 B
    __shared__ __align__(16) _Float16 s_epre16[TT * 128];  // 8192 B
    __shared__ __align__(16) _Float16 s_hcx[4 * 264];      // 4 staggered copies [h|c|pad8]
    __shared__ __align__(16) _Float16 s_A16[128];
    __shared__ __align__(16) _Float16 s_w216[128];
    __shared__ float s_logit[TT];
    __shared__ float s_q[TT];
    __shared__ float s_att[TT];
    __shared__ float s_yh[TT];
    __shared__ float s_ctx[128];
    // ~21 KB

    const int tid = threadIdx.x;
    const int b = blockIdx.x;
    const int lane = tid & 63;
    const int g = tid >> 2, s4 = tid & 3;

    // =========================== stage ===========================
    {
        const float4* encp = (const float4*)(enc_g + (size_t)b * TT * 128);
#pragma unroll
        for (int r = 0; r < 2; r++) {
            int gi = tid * 2 + r;  // 0..1023
            float4 v = encp[gi];
            int t = gi >> 5, e4 = gi & 31;
            h4_t hv;
            hv[0] = (_Float16)v.x; hv[1] = (_Float16)v.y;
            hv[2] = (_Float16)v.z; hv[3] = (_Float16)v.w;
            *(h4_t*)(s_enc16 + t * 136 + e4 * 4) = hv;
        }
    }
    for (int i = tid; i < 528; i += 512) ((unsigned int*)s_hcx)[i] = 0u;
    if (tid < 128) s_w216[tid] = (_Float16)W2[tid];
    if (tid < TT) s_yh[tid] = yh_g[b * TT + tid];

    // W1a quarter (row g, cols s4*64..+64) -> registers (f16), 32 VGPR
    h8_t w1areg[8];
    {
        const float4* p = (const float4*)(W1 + g * 384 + s4 * 64);
#pragma unroll
        for (int k = 0; k < 8; k++) w1areg[k] = pk8(p[2 * k], p[2 * k + 1]);
    }
    // Four gate rows (j*128+g), col slice s4*32..+32 -> registers, 64 VGPR
    h8_t whhreg[4][4];
    float biasr[4], wihr[4];
#pragma unroll
    for (int j = 0; j < 4; j++) {
        const float4* p = (const float4*)(Whh + (size_t)(j * 128 + g) * 128 + s4 * 32);
#pragma unroll
        for (int k = 0; k < 4; k++) whhreg[j][k] = pk8(p[2 * k], p[2 * k + 1]);
        biasr[j] = bih[j * 128 + g] + bhh[j * 128 + g];
        wihr[j] = Wih[j * 128 + g];
    }
    const float b2v = b2[0];
    const float fcw128 = fcW[128];
    const float fcbv = fcB[0];
    const float fcfbv = fcfB[0];
    __syncthreads();

    // ============ Epre[t][g] = b1[g] + W1b[g]@enc[t]  (4 thr/row) ============
    {
        const float4* wp = (const float4*)(W1 + g * 384 + 256 + s4 * 32);
        h8_t wa = pk8(wp[0], wp[1]), wb = pk8(wp[2], wp[3]);
        h8_t wc = pk8(wp[4], wp[5]), wd = pk8(wp[6], wp[7]);
        const float b1v = b1[g];
        for (int t = 0; t < TT; t++) {
            const h8_t* ep8 = (const h8_t*)(s_enc16 + t * 136);
            float pa = dot_h8(wa, ep8[s4 * 4 + 0], 0.f);
            float pb = dot_h8(wb, ep8[s4 * 4 + 1], 0.f);
            pa = dot_h8(wc, ep8[s4 * 4 + 2], pa);
            pb = dot_h8(wd, ep8[s4 * 4 + 3], pb);
            float pp = pa + pb;
            pp += __shfl_xor(pp, 1);
            pp += __shfl_xor(pp, 2);
            if (s4 == 0) s_epre16[t * 128 + g] = (_Float16)(pp + b1v);
        }
    }
    if (tid < 128) {  // q[t] = fcW[0:128] . enc[t]
        const int tq = tid >> 2, sq = tid & 3;
        const float4* fp = (const float4*)(fcW + sq * 32);
        h8_t fa = pk8(fp[0], fp[1]), fb = pk8(fp[2], fp[3]);
        h8_t fc2 = pk8(fp[4], fp[5]), fd = pk8(fp[6], fp[7]);
        const h8_t* ep8 = (const h8_t*)(s_enc16 + tq * 136);
        float pa = dot_h8(fa, ep8[sq * 4 + 0], 0.f);
        float pb = dot_h8(fb, ep8[sq * 4 + 1], 0.f);
        pa = dot_h8(fc2, ep8[sq * 4 + 2], pa);
        pb = dot_h8(fd, ep8[sq * 4 + 3], pb);
        float pq = pa + pb;
        pq += __shfl_xor(pq, 1);
        pq += __shfl_xor(pq, 2);
        if (sq == 0) s_q[tq] = pq;
    }
    float c_reg = 0.f;  // s4==0 threads: fp32 cell state for cell g
    __syncthreads();

    // ============================ scan (32 steps) ============================
    for (int t = 0; t < TT; t++) {
        // ph1: A partial (64-col slice) + all-4-gate partials (32-col slice)
        float gd0, gd1, gd2, gd3;
        {
            const h8_t* hx = ((const h8_t*)s_hcx) + s4 * 33;  // staggered copy s4
            float a0 = 0.f, a1 = 0.f;
            float gp0 = 0.f, gp1 = 0.f, gp2 = 0.f, gp3 = 0.f;
#pragma unroll
            for (int k = 0; k < 4; k++) {
                a0 = dot_h8(w1areg[2 * k], hx[s4 * 8 + 2 * k], a0);
                a1 = dot_h8(w1areg[2 * k + 1], hx[s4 * 8 + 2 * k + 1], a1);
            }
#pragma unroll
            for (int k = 0; k < 4; k++) {
                h8_t hv = hx[s4 * 4 + k];
                gp0 = dot_h8(whhreg[0][k], hv, gp0);
                gp1 = dot_h8(whhreg[1][k], hv, gp1);
                gp2 = dot_h8(whhreg[2][k], hv, gp2);
                gp3 = dot_h8(whhreg[3][k], hv, gp3);
            }
            float aa = a0 + a1;
            aa += __shfl_xor(aa, 1);
            aa += __shfl_xor(aa, 2);
            gp0 += __shfl_xor(gp0, 1);
            gp0 += __shfl_xor(gp0, 2);
            gp1 += __shfl_xor(gp1, 1);
            gp1 += __shfl_xor(gp1, 2);
            gp2 += __shfl_xor(gp2, 1);
            gp2 += __shfl_xor(gp2, 2);
            gp3 += __shfl_xor(gp3, 1);
            gp3 += __shfl_xor(gp3, 2);
            if (s4 == 0) s_A16[g] = (_Float16)aa;
            gd0 = gp0 + biasr[0];
            gd1 = gp1 + biasr[1];
            gd2 = gp2 + biasr[2];
            gd3 = gp3 + biasr[3];
        }
        __syncthreads();  // B1

        // ph2: logits[tt] = b2 + sum_h w2[h]*tanh(A[h]+Epre[tt][h])
        {
            const int tt_ = tid >> 4, sub = tid & 15;
            h8_t ev = ((const h8_t*)(s_epre16 + tt_ * 128))[sub];
            h8_t av = ((const h8_t*)s_A16)[sub];
            h8_t wv = ((const h8_t*)s_w216)[sub];
            float lp = 0.f;
#pragma unroll
            for (int i = 0; i < 8; i++)
                lp += (float)wv[i] * fast_tanh((float)av[i] + (float)ev[i]);
            lp += __shfl_xor(lp, 1);
            lp += __shfl_xor(lp, 2);
            lp += __shfl_xor(lp, 4);
            lp += __shfl_xor(lp, 8);
            if (sub == 0) s_logit[tt_] = lp + b2v;
        }
        __syncthreads();  // B2

        // ph3: every wave: softmax + y_tilde; cell threads: gates from regs
        {
            float el = __expf(s_logit[lane & 31]);
            float ql = s_q[lane & 31];
            float ss = el, ys = el * ql;
#pragma unroll
            for (int m = 1; m <= 16; m <<= 1) {
                ss += __shfl_xor(ss, m);
                ys += __shfl_xor(ys, m);
            }
            float inv = __fdividef(1.f, ss);
            if (t == TT - 1 && tid < TT) s_att[tid] = el * inv;
            float yt = ys * inv + fcw128 * s_yh[t] + fcbv;
            if (s4 == 0) {
                float gi_ = gd0 + wihr[0] * yt;
                float gf_ = gd1 + wihr[1] * yt;
                float gg_ = gd2 + wihr[2] * yt;
                float go_ = gd3 + wihr[3] * yt;
                float cn = fast_sig(gf_) * c_reg + fast_sig(gi_) * fast_tanh(gg_);
                float hn = fast_sig(go_) * fast_tanh(cn);
                c_reg = cn;
                _Float16 hh = (_Float16)hn, cc = (_Float16)cn;
#pragma unroll
                for (int j = 0; j < 4; j++) {
                    s_hcx[j * 264 + g] = hh;
                    s_hcx[j * 264 + 128 + g] = cc;
                }
            }
        }
        __syncthreads();  // B3
    }

    // ============================== epilogue =================================
    if (tid < 128) {
        float acc = 0.f;
#pragma unroll 8
        for (int t2 = 0; t2 < TT; t2++) acc += s_att[t2] * (float)s_enc16[t2 * 136 + tid];
        s_ctx[tid] = acc;
    }
    __syncthreads();
    if (tid < 64) {
        float p = fcfW[lane] * (float)s_hcx[lane] +
                  fcfW[64 + lane] * (float)s_hcx[64 + lane] +
                  fcfW[128 + lane] * s_ctx[lane] +
                  fcfW[192 + lane] * s_ctx[64 + lane];
#pragma unroll
        for (int m = 1; m < 64; m <<= 1) p += __shfl_xor(p, m);
        if (lane == 0) out[b] = p + fcfbv + s_yh[TT - 1];
    }
}

extern "C" void kernel_launch(void* const* d_in, const int* in_sizes, int n_in,
                              void* d_out, int out_size, void* d_ws, size_t ws_size,
                              hipStream_t stream) {
    decoder_kernel<<<256, 512, 0, stream>>>(
        (const float*)d_in[0], (const float*)d_in[1], (const float*)d_in[2],
        (const float*)d_in[3], (const float*)d_in[4], (const float*)d_in[5],
        (const float*)d_in[6], (const float*)d_in[7], (const float*)d_in[8],
        (const float*)d_in[9], (const float*)d_in[10], (const float*)d_in[11],
        (const float*)d_in[12], (const float*)d_in[13], (float*)d_out);
}

// Round 10
// 159.227 us; speedup vs baseline: 1.0771x; 1.0771x over previous
//
#include <hip/hip_runtime.h>

// DA-RNN decoder: 256 blocks (1/CU) x 1024 threads (16 waves), 32 serial steps.
// ALL matvecs on the matrix pipe (mfma_f32_16x16x32_f16, h broadcast in B):
//   waves 0-7:  gate rows 64w..64w+63 (4 row-tiles x 4 k-tiles, frags in regs)
//   waves 8-15: W1a rows 16wa..+15    (1 row-tile x 8 k-tiles over [h;c])
// Shared wf[16] frag array -> per-kernel VGPR ask ~110 (no spill at 128 cap).
// Epre = W1b @ enc^T done as a 128x32x128 MFMA GEMM at setup (4 MFMA/wave).
// ph2 writes e^logit and e*q; ph3 sums 32 floats in-register (no shuffles).
// 3 barriers/step. C/D layout: col=lane&15, row=(lane>>4)*4+reg (verified m89).

#define TT 32

typedef _Float16 h2_t __attribute__((ext_vector_type(2)));
typedef _Float16 h4_t __attribute__((ext_vector_type(4)));
typedef _Float16 f16x8 __attribute__((ext_vector_type(8)));
typedef float f32x4 __attribute__((ext_vector_type(4)));

#if __has_builtin(__builtin_amdgcn_fdot2)
#define FDOT2(a, b, c) __builtin_amdgcn_fdot2((a), (b), (c), false)
#else
static __device__ __forceinline__ float FDOT2(h2_t a, h2_t b, float c) {
    return c + (float)a[0] * (float)b[0] + (float)a[1] * (float)b[1];
}
#endif

__device__ __forceinline__ float dot_h8(f16x8 w, f16x8 v, float acc) {
    acc = FDOT2(__builtin_shufflevector(w, w, 0, 1), __builtin_shufflevector(v, v, 0, 1), acc);
    acc = FDOT2(__builtin_shufflevector(w, w, 2, 3), __builtin_shufflevector(v, v, 2, 3), acc);
    acc = FDOT2(__builtin_shufflevector(w, w, 4, 5), __builtin_shufflevector(v, v, 4, 5), acc);
    acc = FDOT2(__builtin_shufflevector(w, w, 6, 7), __builtin_shufflevector(v, v, 6, 7), acc);
    return acc;
}
__device__ __forceinline__ f16x8 pk8(float4 a, float4 b) {
    f16x8 r;
    r[0] = (_Float16)a.x; r[1] = (_Float16)a.y; r[2] = (_Float16)a.z; r[3] = (_Float16)a.w;
    r[4] = (_Float16)b.x; r[5] = (_Float16)b.y; r[6] = (_Float16)b.z; r[7] = (_Float16)b.w;
    return r;
}
__device__ __forceinline__ float fast_tanh(float x) {
    float e = __expf(2.f * x);
    return 1.f - __fdividef(2.f, e + 1.f);
}
__device__ __forceinline__ float fast_sig(float x) {
    return __fdividef(1.f, 1.f + __expf(-x));
}

#define MFMA(a, b, c) __builtin_amdgcn_mfma_f32_16x16x32_f16((a), (b), (c), 0, 0, 0)

__global__ __launch_bounds__(1024, 4) void decoder_kernel(
    const float* __restrict__ enc_g,  // [B,32,128]
    const float* __restrict__ yh_g,   // [B,32,1]
    const float* __restrict__ W1,     // [128,384] cols [h|c|enc]
    const float* __restrict__ b1,     // [128]
    const float* __restrict__ W2,     // [1,128]
    const float* __restrict__ b2,     // [1]
    const float* __restrict__ Wih,    // [512,1]
    const float* __restrict__ Whh,    // [512,128]
    const float* __restrict__ bih,    // [512]
    const float* __restrict__ bhh,    // [512]
    const float* __restrict__ fcW,    // [1,129]
    const float* __restrict__ fcB,    // [1]
    const float* __restrict__ fcfW,   // [1,256]
    const float* __restrict__ fcfB,   // [1]
    float* __restrict__ out)          // [B,1]
{
    __shared__ __align__(16) _Float16 s_enc16[TT * 136];   // [t][136 pad]
    __shared__ __align__(16) _Float16 s_epre16[TT * 132];  // [t][132 pad]
    __shared__ __align__(16) _Float16 s_hc16[256];         // h[128] | c[128]
    __shared__ __align__(16) _Float16 s_A16[128];
    __shared__ __align__(16) _Float16 s_w216[128];
    __shared__ __align__(16) float s_gdot[512];            // raw Whh@h (no bias)
    __shared__ __align__(16) float s_elog[TT];             // e^logit
    __shared__ __align__(16) float s_eq[TT];               // e^logit * q[t]
    __shared__ __align__(16) float s_qf[TT];
    __shared__ float s_yh[TT];
    __shared__ float s_ctx[128];
    // ~22 KB

    const int tid = threadIdx.x;
    const int b = blockIdx.x;
    const int lane = tid & 63;
    const int wv = tid >> 6;      // wave id 0..15
    const int lrow = lane & 15;   // MFMA row/col selector
    const int lk = lane >> 4;     // MFMA k-group 0..3

    // =========================== stage ===========================
    {
        const float4* encp = (const float4*)(enc_g + (size_t)b * TT * 128);
        float4 v = encp[tid];  // 1024 float4 exactly
        int t = tid >> 5, e4 = tid & 31;
        h4_t hv;
        hv[0] = (_Float16)v.x; hv[1] = (_Float16)v.y;
        hv[2] = (_Float16)v.z; hv[3] = (_Float16)v.w;
        *(h4_t*)(s_enc16 + t * 136 + e4 * 4) = hv;
    }
    if (tid < 256) s_hc16[tid] = (_Float16)0.f;
    if (tid < 128) s_w216[tid] = (_Float16)W2[tid];
    if (tid < TT) s_yh[tid] = yh_g[b * TT + tid];
    const float b2v = b2[0];
    const float fcw128 = fcW[128];
    const float fcbv = fcB[0];
    const float fcfbv = fcfB[0];
    __syncthreads();  // enc staged

    // ====== Epre[t][h] = b1[h] + W1b @ enc^T : 128x32x128 MFMA GEMM ==========
    {
        const int rt = wv >> 1, ct = wv & 1;  // row-tile 0..7, col(t)-tile 0..1
        f32x4 cE = {0.f, 0.f, 0.f, 0.f};
#pragma unroll
        for (int kt = 0; kt < 4; kt++) {
            const float* ap = W1 + (16 * rt + lrow) * 384 + 256 + 32 * kt + 8 * lk;
            f16x8 af = pk8(*(const float4*)ap, *(const float4*)(ap + 4));
            f16x8 bf = *(const f16x8*)(s_enc16 + (16 * ct + lrow) * 136 + 32 * kt + 8 * lk);
            cE = MFMA(af, bf, cE);
        }
        float4 b1v = *(const float4*)(b1 + 16 * rt + 4 * lk);
        h4_t o;
        o[0] = (_Float16)(cE[0] + b1v.x);
        o[1] = (_Float16)(cE[1] + b1v.y);
        o[2] = (_Float16)(cE[2] + b1v.z);
        o[3] = (_Float16)(cE[3] + b1v.w);
        const int tcol = 16 * ct + lrow;
        *(h4_t*)(s_epre16 + tcol * 132 + 16 * rt + 4 * lk) = o;
    }

    // ====== q[t] = fcW[0:128] . enc[t]  (tid<128, VALU, once) ================
    if (tid < 128) {
        const int tq = tid >> 2, sq = tid & 3;
        const float4* fp = (const float4*)(fcW + sq * 32);
        f16x8 fa_ = pk8(fp[0], fp[1]), fb_ = pk8(fp[2], fp[3]);
        f16x8 fc_ = pk8(fp[4], fp[5]), fd_ = pk8(fp[6], fp[7]);
        const f16x8* ep8 = (const f16x8*)(s_enc16 + tq * 136);
        float pa = dot_h8(fa_, ep8[sq * 4 + 0], 0.f);
        float pb = dot_h8(fb_, ep8[sq * 4 + 1], 0.f);
        pa = dot_h8(fc_, ep8[sq * 4 + 2], pa);
        pb = dot_h8(fd_, ep8[sq * 4 + 3], pb);
        float pq = pa + pb;
        pq += __shfl_xor(pq, 1);
        pq += __shfl_xor(pq, 2);
        if (sq == 0) s_qf[tq] = pq;
    }

    // ====== persistent MFMA A-frags (shared array, role-split waves) =========
    f16x8 wf[16];
    if (wv < 8) {  // gate waves: rows 64wv+16rt+lrow, k-slice 32kt+8lk
#pragma unroll
        for (int rt = 0; rt < 4; rt++)
#pragma unroll
            for (int kt = 0; kt < 4; kt++) {
                const float* p = Whh + (size_t)(64 * wv + 16 * rt + lrow) * 128 + 32 * kt + 8 * lk;
                wf[rt * 4 + kt] = pk8(*(const float4*)p, *(const float4*)(p + 4));
            }
    } else {  // attn waves: W1a rows 16wa+lrow, k over [h;c] = W1 cols 0..255
        const int wa = wv - 8;
#pragma unroll
        for (int kt = 0; kt < 8; kt++) {
            const float* p = W1 + (16 * wa + lrow) * 384 + 32 * kt + 8 * lk;
            wf[kt] = pk8(*(const float4*)p, *(const float4*)(p + 4));
        }
    }
    float biasr0 = 0.f, biasr1 = 0.f, biasr2 = 0.f, biasr3 = 0.f;
    float wihr0 = 0.f, wihr1 = 0.f, wihr2 = 0.f, wihr3 = 0.f;
    if (tid < 128) {
        biasr0 = bih[tid] + bhh[tid];
        biasr1 = bih[128 + tid] + bhh[128 + tid];
        biasr2 = bih[256 + tid] + bhh[256 + tid];
        biasr3 = bih[384 + tid] + bhh[384 + tid];
        wihr0 = Wih[tid]; wihr1 = Wih[128 + tid];
        wihr2 = Wih[256 + tid]; wihr3 = Wih[384 + tid];
    }
    float c_reg = 0.f;  // tid<128: fp32 cell state
    __syncthreads();    // epre, q, frags, hc ready

    // ============================ scan (32 steps) ============================
    for (int t = 0; t < TT; t++) {
        // ---- ph1: matvecs on matrix pipe (B = broadcast h / [h;c]) ----
        if (wv < 8) {
            f16x8 hb0 = *(const f16x8*)(s_hc16 + 0 + 8 * lk);
            f16x8 hb1 = *(const f16x8*)(s_hc16 + 32 + 8 * lk);
            f16x8 hb2 = *(const f16x8*)(s_hc16 + 64 + 8 * lk);
            f16x8 hb3 = *(const f16x8*)(s_hc16 + 96 + 8 * lk);
            f32x4 c0 = {0.f, 0.f, 0.f, 0.f}, c1 = c0, c2 = c0, c3 = c0;
            c0 = MFMA(wf[0], hb0, c0);  c1 = MFMA(wf[4], hb0, c1);
            c2 = MFMA(wf[8], hb0, c2);  c3 = MFMA(wf[12], hb0, c3);
            c0 = MFMA(wf[1], hb1, c0);  c1 = MFMA(wf[5], hb1, c1);
            c2 = MFMA(wf[9], hb1, c2);  c3 = MFMA(wf[13], hb1, c3);
            c0 = MFMA(wf[2], hb2, c0);  c1 = MFMA(wf[6], hb2, c1);
            c2 = MFMA(wf[10], hb2, c2); c3 = MFMA(wf[14], hb2, c3);
            c0 = MFMA(wf[3], hb3, c0);  c1 = MFMA(wf[7], hb3, c1);
            c2 = MFMA(wf[11], hb3, c2); c3 = MFMA(wf[15], hb3, c3);
            if (lrow == 0) {  // lanes 0,16,32,48 hold rows 4lk..4lk+3 (col 0)
                *(f32x4*)(s_gdot + 64 * wv + 0 + 4 * lk) = c0;
                *(f32x4*)(s_gdot + 64 * wv + 16 + 4 * lk) = c1;
                *(f32x4*)(s_gdot + 64 * wv + 32 + 4 * lk) = c2;
                *(f32x4*)(s_gdot + 64 * wv + 48 + 4 * lk) = c3;
            }
        } else {
            const int wa = wv - 8;
            f32x4 ca = {0.f, 0.f, 0.f, 0.f};
#pragma unroll
            for (int kt = 0; kt < 8; kt++) {
                f16x8 hb = *(const f16x8*)(s_hc16 + kt * 32 + 8 * lk);
                ca = MFMA(wf[kt], hb, ca);
            }
            if (lrow == 0) {
                h4_t o;
                o[0] = (_Float16)ca[0]; o[1] = (_Float16)ca[1];
                o[2] = (_Float16)ca[2]; o[3] = (_Float16)ca[3];
                *(h4_t*)(s_A16 + 16 * wa + 4 * lk) = o;
            }
        }
        __syncthreads();  // B1

        // ---- ph2: logits; writer stores e^logit and e*q (32 thr/t, 4 tanh) --
        {
            const int tt_ = tid >> 5, sub = tid & 31;
            h4_t ev = *(const h4_t*)(s_epre16 + tt_ * 132 + sub * 4);
            h4_t av = *(const h4_t*)(s_A16 + sub * 4);
            h4_t wv2 = *(const h4_t*)(s_w216 + sub * 4);
            float lp = (float)wv2[0] * fast_tanh((float)av[0] + (float)ev[0]) +
                       (float)wv2[1] * fast_tanh((float)av[1] + (float)ev[1]) +
                       (float)wv2[2] * fast_tanh((float)av[2] + (float)ev[2]) +
                       (float)wv2[3] * fast_tanh((float)av[3] + (float)ev[3]);
            lp += __shfl_xor(lp, 1);
            lp += __shfl_xor(lp, 2);
            lp += __shfl_xor(lp, 4);
            lp += __shfl_xor(lp, 8);
            lp += __shfl_xor(lp, 16);
            if (sub == 0) {
                float el = __expf(lp + b2v);
                s_elog[tt_] = el;
                s_eq[tt_] = el * s_qf[tt_];
            }
        }
        __syncthreads();  // B2

        // ---- ph3 (tid<128): in-register softmax sums -> y_tilde -> LSTM ----
        if (tid < 128) {
            float gdi = s_gdot[tid];          // issue early, independent
            float gdf = s_gdot[128 + tid];
            float gdg = s_gdot[256 + tid];
            float gdo = s_gdot[384 + tid];
            const f32x4* ep = (const f32x4*)s_elog;
            const f32x4* qp = (const f32x4*)s_eq;
            f32x4 se = (ep[0] + ep[1]) + (ep[2] + ep[3]) + (ep[4] + ep[5]) + (ep[6] + ep[7]);
            f32x4 sy = (qp[0] + qp[1]) + (qp[2] + qp[3]) + (qp[4] + qp[5]) + (qp[6] + qp[7]);
            float ss = (se[0] + se[1]) + (se[2] + se[3]);
            float ys = (sy[0] + sy[1]) + (sy[2] + sy[3]);
            float yt = __fdividef(ys, ss) + fcw128 * s_yh[t] + fcbv;
            float gi_ = gdi + biasr0 + wihr0 * yt;
            float gf_ = gdf + biasr1 + wihr1 * yt;
            float gg_ = gdg + biasr2 + wihr2 * yt;
            float go_ = gdo + biasr3 + wihr3 * yt;
            float cn = fast_sig(gf_) * c_reg + fast_sig(gi_) * fast_tanh(gg_);
            float hn = fast_sig(go_) * fast_tanh(cn);
            c_reg = cn;
            s_hc16[tid] = (_Float16)hn;
            s_hc16[128 + tid] = (_Float16)cn;
        }
        __syncthreads();  // B3
    }

    // ============================== epilogue =================================
    if (tid < 128) {
        const f32x4* ep = (const f32x4*)s_elog;
        f32x4 se = (ep[0] + ep[1]) + (ep[2] + ep[3]) + (ep[4] + ep[5]) + (ep[6] + ep[7]);
        float inv = __fdividef(1.f, (se[0] + se[1]) + (se[2] + se[3]));
        float acc = 0.f;
#pragma unroll 8
        for (int t2 = 0; t2 < TT; t2++)
            acc += s_elog[t2] * (float)s_enc16[t2 * 136 + tid];
        s_ctx[tid] = acc * inv;
    }
    __syncthreads();
    if (tid < 64) {
        float p = fcfW[lane] * (float)s_hc16[lane] +
                  fcfW[64 + lane] * (float)s_hc16[64 + lane] +
                  fcfW[128 + lane] * s_ctx[lane] +
                  fcfW[192 + lane] * s_ctx[64 + lane];
#pragma unroll
        for (int m = 1; m < 64; m <<= 1) p += __shfl_xor(p, m);
        if (lane == 0) out[b] = p + fcfbv + s_yh[TT - 1];
    }
}

extern "C" void kernel_launch(void* const* d_in, const int* in_sizes, int n_in,
                              void* d_out, int out_size, void* d_ws, size_t ws_size,
                              hipStream_t stream) {
    decoder_kernel<<<256, 1024, 0, stream>>>(
        (const float*)d_in[0], (const float*)d_in[1], (const float*)d_in[2],
        (const float*)d_in[3], (const float*)d_in[4], (const float*)d_in[5],
        (const float*)d_in[6], (const float*)d_in[7], (const float*)d_in[8],
        (const float*)d_in[9], (const float*)d_in[10], (const float*)d_in[11],
        (const float*)d_in[12], (const float*)d_in[13], (float*)d_out);
}

// Round 12
// 157.075 us; speedup vs baseline: 1.0919x; 1.0137x over previous
//
#include <hip/hip_runtime.h>

// DA-RNN decoder: 256 blocks (1/CU) x 1024 threads (16 waves), 32 serial steps.
// ph1 matvecs on matrix pipe (mfma_f32_16x16x32_f16, h broadcast in B):
//   waves 0-7:  Whh gate rows (4 row-tiles x 4 k-tiles, frags in regs)
//   waves 8-15: W1a rows 16wa..+15 (8 k-tiles over [h;c])
// ph2: logits with f32 operands (Epre/A/W2 f32 in LDS; A written straight from
//   MFMA f32 accum) and DPP-based 32-lane reduce (5 dpp-adds, ~4cy/level, vs
//   5 ds_bpermute ~60cy/level); writer lane folds exp -> e, e*q.
// ph3 (tid<128): in-register softmax sums -> y_tilde -> LSTM (no shuffles).
// 3 barriers/step. C/D layout col=lane&15, row=(lane>>4)*4+reg (m89).
// (R11 resubmit: dpp ctrl is now a template immediate — compile fix only.)

#define TT 32

typedef _Float16 h2_t __attribute__((ext_vector_type(2)));
typedef _Float16 h4_t __attribute__((ext_vector_type(4)));
typedef _Float16 f16x8 __attribute__((ext_vector_type(8)));
typedef float f32x4 __attribute__((ext_vector_type(4)));

#if __has_builtin(__builtin_amdgcn_fdot2)
#define FDOT2(a, b, c) __builtin_amdgcn_fdot2((a), (b), (c), false)
#else
static __device__ __forceinline__ float FDOT2(h2_t a, h2_t b, float c) {
    return c + (float)a[0] * (float)b[0] + (float)a[1] * (float)b[1];
}
#endif

__device__ __forceinline__ float dot_h8(f16x8 w, f16x8 v, float acc) {
    acc = FDOT2(__builtin_shufflevector(w, w, 0, 1), __builtin_shufflevector(v, v, 0, 1), acc);
    acc = FDOT2(__builtin_shufflevector(w, w, 2, 3), __builtin_shufflevector(v, v, 2, 3), acc);
    acc = FDOT2(__builtin_shufflevector(w, w, 4, 5), __builtin_shufflevector(v, v, 4, 5), acc);
    acc = FDOT2(__builtin_shufflevector(w, w, 6, 7), __builtin_shufflevector(v, v, 6, 7), acc);
    return acc;
}
__device__ __forceinline__ f16x8 pk8(float4 a, float4 b) {
    f16x8 r;
    r[0] = (_Float16)a.x; r[1] = (_Float16)a.y; r[2] = (_Float16)a.z; r[3] = (_Float16)a.w;
    r[4] = (_Float16)b.x; r[5] = (_Float16)b.y; r[6] = (_Float16)b.z; r[7] = (_Float16)b.w;
    return r;
}
__device__ __forceinline__ float fast_tanh(float x) {
    float e = __expf(2.f * x);
    return 1.f - __fdividef(2.f, e + 1.f);
}
__device__ __forceinline__ float fast_sig(float x) {
    return __fdividef(1.f, 1.f + __expf(-x));
}

#define MFMA(a, b, c) __builtin_amdgcn_mfma_f32_16x16x32_f16((a), (b), (c), 0, 0, 0)

// ---- 32-lane sum via DPP (result valid in lanes 31 and 63) ----
#if __has_builtin(__builtin_amdgcn_update_dpp)
template <int CTRL>
__device__ __forceinline__ float dpp_add(float x) {
    int y = __builtin_amdgcn_update_dpp(0, __float_as_int(x), CTRL, 0xF, 0xF, false);
    return x + __int_as_float(y);
}
__device__ __forceinline__ float sum32_dpp(float x) {
    x = dpp_add<0x111>(x);  // row_shr:1
    x = dpp_add<0x112>(x);  // row_shr:2
    x = dpp_add<0x114>(x);  // row_shr:4
    x = dpp_add<0x118>(x);  // row_shr:8  -> lane15/31/47/63 hold row sums
    x = dpp_add<0x142>(x);  // row_bcast15 -> lanes 31,63 hold 32-lane sums
    return x;
}
#else
__device__ __forceinline__ float sum32_dpp(float x) {
    x += __shfl_xor(x, 1); x += __shfl_xor(x, 2); x += __shfl_xor(x, 4);
    x += __shfl_xor(x, 8); x += __shfl_xor(x, 16);
    return x;
}
#endif

__global__ __launch_bounds__(1024, 4) void decoder_kernel(
    const float* __restrict__ enc_g,  // [B,32,128]
    const float* __restrict__ yh_g,   // [B,32,1]
    const float* __restrict__ W1,     // [128,384] cols [h|c|enc]
    const float* __restrict__ b1,     // [128]
    const float* __restrict__ W2,     // [1,128]
    const float* __restrict__ b2,     // [1]
    const float* __restrict__ Wih,    // [512,1]
    const float* __restrict__ Whh,    // [512,128]
    const float* __restrict__ bih,    // [512]
    const float* __restrict__ bhh,    // [512]
    const float* __restrict__ fcW,    // [1,129]
    const float* __restrict__ fcB,    // [1]
    const float* __restrict__ fcfW,   // [1,256]
    const float* __restrict__ fcfB,   // [1]
    float* __restrict__ out)          // [B,1]
{
    __shared__ __align__(16) _Float16 s_enc16[TT * 136];  // 8704 B
    __shared__ __align__(16) float s_epre[TT * 132];      // 16896 B (f32)
    __shared__ __align__(16) _Float16 s_hc16[256];        // h[128] | c[128]
    __shared__ __align__(16) float s_A[128];              // f32
    __shared__ __align__(16) float s_w2[128];             // f32
    __shared__ __align__(16) float s_gdot[512];           // raw Whh@h
    __shared__ __align__(16) float s_elog[TT];
    __shared__ __align__(16) float s_eq[TT];
    __shared__ __align__(16) float s_qf[TT];
    __shared__ float s_yh[TT];
    __shared__ float s_ctx[128];
    // ~31 KB

    const int tid = threadIdx.x;
    const int b = blockIdx.x;
    const int lane = tid & 63;
    const int wv = tid >> 6;      // wave id 0..15
    const int lrow = lane & 15;   // MFMA row/col selector
    const int lk = lane >> 4;     // MFMA k-group 0..3

    // =========================== stage ===========================
    {
        const float4* encp = (const float4*)(enc_g + (size_t)b * TT * 128);
        float4 v = encp[tid];  // 1024 float4 exactly
        int t = tid >> 5, e4 = tid & 31;
        h4_t hv;
        hv[0] = (_Float16)v.x; hv[1] = (_Float16)v.y;
        hv[2] = (_Float16)v.z; hv[3] = (_Float16)v.w;
        *(h4_t*)(s_enc16 + t * 136 + e4 * 4) = hv;
    }
    if (tid < 256) s_hc16[tid] = (_Float16)0.f;
    if (tid < 128) s_w2[tid] = W2[tid];
    if (tid < TT) s_yh[tid] = yh_g[b * TT + tid];
    const float b2v = b2[0];
    const float fcw128 = fcW[128];
    const float fcbv = fcB[0];
    const float fcfbv = fcfB[0];
    __syncthreads();  // enc staged

    // ====== Epre[t][h] = b1[h] + W1b @ enc^T : 128x32x128 MFMA GEMM (f32 out)
    {
        const int rt = wv >> 1, ct = wv & 1;  // row-tile 0..7, col(t)-tile 0..1
        f32x4 cE = {0.f, 0.f, 0.f, 0.f};
#pragma unroll
        for (int kt = 0; kt < 4; kt++) {
            const float* ap = W1 + (16 * rt + lrow) * 384 + 256 + 32 * kt + 8 * lk;
            f16x8 af = pk8(*(const float4*)ap, *(const float4*)(ap + 4));
            f16x8 bf = *(const f16x8*)(s_enc16 + (16 * ct + lrow) * 136 + 32 * kt + 8 * lk);
            cE = MFMA(af, bf, cE);
        }
        float4 b1v = *(const float4*)(b1 + 16 * rt + 4 * lk);
        f32x4 o;
        o[0] = cE[0] + b1v.x; o[1] = cE[1] + b1v.y;
        o[2] = cE[2] + b1v.z; o[3] = cE[3] + b1v.w;
        const int tcol = 16 * ct + lrow;
        *(f32x4*)(s_epre + tcol * 132 + 16 * rt + 4 * lk) = o;
    }

    // ====== q[t] = fcW[0:128] . enc[t]  (tid<128, once) ======================
    if (tid < 128) {
        const int tq = tid >> 2, sq = tid & 3;
        const float4* fp = (const float4*)(fcW + sq * 32);
        f16x8 fa_ = pk8(fp[0], fp[1]), fb_ = pk8(fp[2], fp[3]);
        f16x8 fc_ = pk8(fp[4], fp[5]), fd_ = pk8(fp[6], fp[7]);
        const f16x8* ep8 = (const f16x8*)(s_enc16 + tq * 136);
        float pa = dot_h8(fa_, ep8[sq * 4 + 0], 0.f);
        float pb = dot_h8(fb_, ep8[sq * 4 + 1], 0.f);
        pa = dot_h8(fc_, ep8[sq * 4 + 2], pa);
        pb = dot_h8(fd_, ep8[sq * 4 + 3], pb);
        float pq = pa + pb;
        pq += __shfl_xor(pq, 1);
        pq += __shfl_xor(pq, 2);
        if (sq == 0) s_qf[tq] = pq;
    }

    // ====== persistent MFMA A-frags (shared array, role-split waves) =========
    f16x8 wf[16];
    if (wv < 8) {  // gate waves
#pragma unroll
        for (int rt = 0; rt < 4; rt++)
#pragma unroll
            for (int kt = 0; kt < 4; kt++) {
                const float* p = Whh + (size_t)(64 * wv + 16 * rt + lrow) * 128 + 32 * kt + 8 * lk;
                wf[rt * 4 + kt] = pk8(*(const float4*)p, *(const float4*)(p + 4));
            }
    } else {  // attn waves
        const int wa = wv - 8;
#pragma unroll
        for (int kt = 0; kt < 8; kt++) {
            const float* p = W1 + (16 * wa + lrow) * 384 + 32 * kt + 8 * lk;
            wf[kt] = pk8(*(const float4*)p, *(const float4*)(p + 4));
        }
    }
    float biasr0 = 0.f, biasr1 = 0.f, biasr2 = 0.f, biasr3 = 0.f;
    float wihr0 = 0.f, wihr1 = 0.f, wihr2 = 0.f, wihr3 = 0.f;
    if (tid < 128) {
        biasr0 = bih[tid] + bhh[tid];
        biasr1 = bih[128 + tid] + bhh[128 + tid];
        biasr2 = bih[256 + tid] + bhh[256 + tid];
        biasr3 = bih[384 + tid] + bhh[384 + tid];
        wihr0 = Wih[tid]; wihr1 = Wih[128 + tid];
        wihr2 = Wih[256 + tid]; wihr3 = Wih[384 + tid];
    }
    float c_reg = 0.f;  // tid<128: fp32 cell state
    __syncthreads();    // epre, q, frags, hc ready

    // ============================ scan (32 steps) ============================
    for (int t = 0; t < TT; t++) {
        // ---- ph1: matvecs on matrix pipe (B = broadcast h / [h;c]) ----
        if (wv < 8) {
            f16x8 hb0 = *(const f16x8*)(s_hc16 + 0 + 8 * lk);
            f16x8 hb1 = *(const f16x8*)(s_hc16 + 32 + 8 * lk);
            f16x8 hb2 = *(const f16x8*)(s_hc16 + 64 + 8 * lk);
            f16x8 hb3 = *(const f16x8*)(s_hc16 + 96 + 8 * lk);
            f32x4 c0 = {0.f, 0.f, 0.f, 0.f}, c1 = c0, c2 = c0, c3 = c0;
            c0 = MFMA(wf[0], hb0, c0);  c1 = MFMA(wf[4], hb0, c1);
            c2 = MFMA(wf[8], hb0, c2);  c3 = MFMA(wf[12], hb0, c3);
            c0 = MFMA(wf[1], hb1, c0);  c1 = MFMA(wf[5], hb1, c1);
            c2 = MFMA(wf[9], hb1, c2);  c3 = MFMA(wf[13], hb1, c3);
            c0 = MFMA(wf[2], hb2, c0);  c1 = MFMA(wf[6], hb2, c1);
            c2 = MFMA(wf[10], hb2, c2); c3 = MFMA(wf[14], hb2, c3);
            c0 = MFMA(wf[3], hb3, c0);  c1 = MFMA(wf[7], hb3, c1);
            c2 = MFMA(wf[11], hb3, c2); c3 = MFMA(wf[15], hb3, c3);
            if (lrow == 0) {  // lanes 0,16,32,48 hold rows 4lk..4lk+3 (col 0)
                *(f32x4*)(s_gdot + 64 * wv + 0 + 4 * lk) = c0;
                *(f32x4*)(s_gdot + 64 * wv + 16 + 4 * lk) = c1;
                *(f32x4*)(s_gdot + 64 * wv + 32 + 4 * lk) = c2;
                *(f32x4*)(s_gdot + 64 * wv + 48 + 4 * lk) = c3;
            }
        } else {
            const int wa = wv - 8;
            f32x4 ca = {0.f, 0.f, 0.f, 0.f};
#pragma unroll
            for (int kt = 0; kt < 8; kt++) {
                f16x8 hb = *(const f16x8*)(s_hc16 + kt * 32 + 8 * lk);
                ca = MFMA(wf[kt], hb, ca);
            }
            if (lrow == 0) *(f32x4*)(s_A + 16 * wa + 4 * lk) = ca;  // f32 direct
        }
        __syncthreads();  // B1

        // ---- ph2: logits, f32 operands, DPP reduce; writer lane folds exp --
        {
            const int tt_ = tid >> 5, sub = tid & 31;
            float4 ev = *(const float4*)(s_epre + tt_ * 132 + sub * 4);
            float4 av = *(const float4*)(s_A + sub * 4);
            float4 wv2 = *(const float4*)(s_w2 + sub * 4);
            float lp = wv2.x * fast_tanh(av.x + ev.x) +
                       wv2.y * fast_tanh(av.y + ev.y) +
                       wv2.z * fast_tanh(av.z + ev.z) +
                       wv2.w * fast_tanh(av.w + ev.w);
            float s = sum32_dpp(lp);  // valid in lanes 31, 63
            if (sub == 31) {
                float el = __expf(s + b2v);
                s_elog[tt_] = el;
                s_eq[tt_] = el * s_qf[tt_];
            }
        }
        __syncthreads();  // B2

        // ---- ph3 (tid<128): in-register softmax sums -> y_tilde -> LSTM ----
        if (tid < 128) {
            float gdi = s_gdot[tid];
            float gdf = s_gdot[128 + tid];
            float gdg = s_gdot[256 + tid];
            float gdo = s_gdot[384 + tid];
            const f32x4* ep = (const f32x4*)s_elog;
            const f32x4* qp = (const f32x4*)s_eq;
            f32x4 se = (ep[0] + ep[1]) + (ep[2] + ep[3]) + (ep[4] + ep[5]) + (ep[6] + ep[7]);
            f32x4 sy = (qp[0] + qp[1]) + (qp[2] + qp[3]) + (qp[4] + qp[5]) + (qp[6] + qp[7]);
            float ss = (se[0] + se[1]) + (se[2] + se[3]);
            float ys = (sy[0] + sy[1]) + (sy[2] + sy[3]);
            float yt = __fdividef(ys, ss) + fcw128 * s_yh[t] + fcbv;
            float gi_ = gdi + biasr0 + wihr0 * yt;
            float gf_ = gdf + biasr1 + wihr1 * yt;
            float gg_ = gdg + biasr2 + wihr2 * yt;
            float go_ = gdo + biasr3 + wihr3 * yt;
            float cn = fast_sig(gf_) * c_reg + fast_sig(gi_) * fast_tanh(gg_);
            float hn = fast_sig(go_) * fast_tanh(cn);
            c_reg = cn;
            s_hc16[tid] = (_Float16)hn;
            s_hc16[128 + tid] = (_Float16)cn;
        }
        __syncthreads();  // B3
    }

    // ============================== epilogue =================================
    if (tid < 128) {
        const f32x4* ep = (const f32x4*)s_elog;
        f32x4 se = (ep[0] + ep[1]) + (ep[2] + ep[3]) + (ep[4] + ep[5]) + (ep[6] + ep[7]);
        float inv = __fdividef(1.f, (se[0] + se[1]) + (se[2] + se[3]));
        float acc = 0.f;
#pragma unroll 8
        for (int t2 = 0; t2 < TT; t2++)
            acc += s_elog[t2] * (float)s_enc16[t2 * 136 + tid];
        s_ctx[tid] = acc * inv;
    }
    __syncthreads();
    if (tid < 64) {
        float p = fcfW[lane] * (float)s_hc16[lane] +
                  fcfW[64 + lane] * (float)s_hc16[64 + lane] +
                  fcfW[128 + lane] * s_ctx[lane] +
                  fcfW[192 + lane] * s_ctx[64 + lane];
#pragma unroll
        for (int m = 1; m < 64; m <<= 1) p += __shfl_xor(p, m);
        if (lane == 0) out[b] = p + fcfbv + s_yh[TT - 1];
    }
}

extern "C" void kernel_launch(void* const* d_in, const int* in_sizes, int n_in,
                              void* d_out, int out_size, void* d_ws, size_t ws_size,
                              hipStream_t stream) {
    decoder_kernel<<<256, 1024, 0, stream>>>(
        (const float*)d_in[0], (const float*)d_in[1], (const float*)d_in[2],
        (const float*)d_in[3], (const float*)d_in[4], (const float*)d_in[5],
        (const float*)d_in[6], (const float*)d_in[7], (const float*)d_in[8],
        (const float*)d_in[9], (const float*)d_in[10], (const float*)d_in[11],
        (const float*)d_in[12], (const float*)d_in[13], (float*)d_out);
}